// Round 2
// baseline (970.269 us; speedup 1.0000x reference)
//
#include <hip/hip_runtime.h>
#include <math.h>

// Problem constants (B=16, H=8, L1=307, L2=12, D=64)
#define NGROUPS 39296            // 16*8*307
#define GROUP_ELEMS 768          // 12*64
#define MAT_STRIDE 30179328LL    // NGROUPS*768 (one output tensor)
#define WAVES_PER_BLOCK 4

typedef float f32x4 __attribute__((ext_vector_type(4)));
typedef short bf16x8 __attribute__((ext_vector_type(8)));

// fp32 -> bf16 (round-to-nearest-even), bit-level
static __device__ __forceinline__ short f2bf(float f) {
    unsigned u = __builtin_bit_cast(unsigned, f);
    u += 0x7fffu + ((u >> 16) & 1u);
    return (short)(u >> 16);
}
static __device__ __forceinline__ float bf2f(short s) {
    unsigned u = ((unsigned)(unsigned short)s) << 16;
    return __builtin_bit_cast(float, u);
}

static __device__ __forceinline__ void cvt8(const float4& lo, const float4& hi, bf16x8& f) {
    f[0] = f2bf(lo.x); f[1] = f2bf(lo.y); f[2] = f2bf(lo.z); f[3] = f2bf(lo.w);
    f[4] = f2bf(hi.x); f[5] = f2bf(hi.y); f[6] = f2bf(hi.z); f[7] = f2bf(hi.w);
}

__global__ __launch_bounds__(256) void tsdp_kernel(
    const float* __restrict__ Qf, const float* __restrict__ Kf,
    const float* __restrict__ Vf, const float* __restrict__ Qs,
    const float* __restrict__ Ks, const float* __restrict__ Vs,
    const float* __restrict__ Kj, const float* __restrict__ Vfp,
    const int* __restrict__ mask, float* __restrict__ out)
{
    // Per-wave LDS: 4 matrices x (16 rows x 32 cols) bf16 for the P (z) transpose.
    __shared__ short zP[WAVES_PER_BLOCK][4 * 512];

    const int tid  = threadIdx.x;
    const int wave = tid >> 6;
    const int lane = tid & 63;
    const int quad = lane >> 4;    // 0..3
    const int col  = lane & 15;    // 0..15
    const int g    = blockIdx.x * WAVES_PER_BLOCK + wave;   // group id (exact grid)

    short* zp = zP[wave];
    // Zero the whole zP slice (cols 16..31 must be 0 for the K=32 pad; cols 12..15
    // get true z=0 from the softmax of -inf-padded columns).
    {
        int4 zz = make_int4(0, 0, 0, 0);
        int4* p = (int4*)zp;
        p[lane] = zz; p[lane + 64] = zz; p[lane + 128] = zz; p[lane + 192] = zz;
    }

    const long base = (long)g * GROUP_ELEMS;
    const int  r    = (col < 12) ? col : 11;         // clamped tile row for frag loads
    const long rowoff = base + (long)r * 64 + quad * 8;

    // -------- Score-phase fragments: global fp32 -> bf16 registers, no LDS --------
    // Fragment layout (16x16x32 bf16): row m/n = lane&15, k = quad*8 + j (+32*chunk).
    // s_fs needs split precision: Qfs = Kj*(q - q^2/(Vfp+1e-5)) is unbounded (small
    // Vfp -> O(100) entries -> O(50) scores); single-bf16 operand rounding (2^-9)
    // gives ~0.1-0.2 absolute score error which softmax amplifies past threshold.
    // Split Kf and Qfs into hi+lo bf16 pairs => operand rel err ~2^-17.
    bf16x8 fQf[2], fKf[2], fQs[2], fKs[2], fQfs[2];
    bf16x8 fKfLo[2], fQfsLo[2];
    const float kjv = Kj[r];
    const float rvf = 1.0f / (Vfp[r] + 1e-5f);
    #pragma unroll
    for (int c = 0; c < 2; ++c) {
        const float4 qf0 = *(const float4*)(Qf + rowoff + c * 32);
        const float4 qf1 = *(const float4*)(Qf + rowoff + c * 32 + 4);
        const float4 kf0 = *(const float4*)(Kf + rowoff + c * 32);
        const float4 kf1 = *(const float4*)(Kf + rowoff + c * 32 + 4);
        const float4 ks0 = *(const float4*)(Ks + rowoff + c * 32);
        const float4 ks1 = *(const float4*)(Ks + rowoff + c * 32 + 4);
        const float4 qs0 = *(const float4*)(Qs + rowoff + c * 32);
        const float4 qs1 = *(const float4*)(Qs + rowoff + c * 32 + 4);
        cvt8(qf0, qf1, fQf[c]);
        cvt8(kf0, kf1, fKf[c]);
        cvt8(ks0, ks1, fKs[c]);
        cvt8(qs0, qs1, fQs[c]);
        // Kf residual (lo part)
        float kv[8] = {kf0.x, kf0.y, kf0.z, kf0.w, kf1.x, kf1.y, kf1.z, kf1.w};
        #pragma unroll
        for (int j = 0; j < 8; ++j)
            fKfLo[c][j] = f2bf(kv[j] - bf2f(fKf[c][j]));
        // flow_speed in fp32: Kj*(q - q*q/(Vfp+1e-5)); then hi/lo bf16 split
        float qv[8] = {qs0.x, qs0.y, qs0.z, qs0.w, qs1.x, qs1.y, qs1.z, qs1.w};
        #pragma unroll
        for (int j = 0; j < 8; ++j) {
            float q = qv[j];
            float qfs = kjv * (q - q * q * rvf);
            short hi = f2bf(qfs);
            fQfs[c][j] = hi;
            fQfsLo[c][j] = f2bf(qfs - bf2f(hi));
        }
    }

    // -------- Four score GEMMs (K=64 -> 2 MFMA each; s_fs gets 3x split-MFMA) ----
    f32x4 zero4 = {0.f, 0.f, 0.f, 0.f};
    f32x4 sff = zero4, sfs = zero4, ssf = zero4, sss = zero4;
    #pragma unroll
    for (int c = 0; c < 2; ++c) {
        sff = __builtin_amdgcn_mfma_f32_16x16x32_bf16(fQf[c], fKf[c],  sff, 0, 0, 0); // Qf . Kf^T
        sfs = __builtin_amdgcn_mfma_f32_16x16x32_bf16(fKf[c],   fQfs[c],   sfs, 0, 0, 0); // hi.hi
        sfs = __builtin_amdgcn_mfma_f32_16x16x32_bf16(fKf[c],   fQfsLo[c], sfs, 0, 0, 0); // hi.lo
        sfs = __builtin_amdgcn_mfma_f32_16x16x32_bf16(fKfLo[c], fQfs[c],   sfs, 0, 0, 0); // lo.hi
        ssf = __builtin_amdgcn_mfma_f32_16x16x32_bf16(fKs[c], fQf[c],  ssf, 0, 0, 0); // Ks . Qf^T
        sss = __builtin_amdgcn_mfma_f32_16x16x32_bf16(fQs[c], fKs[c],  sss, 0, 0, 0); // Qs . Ks^T
    }

    // Mask values for this lane's C elements: (row q = quad*4+r2, col = lane&15)
    int mrow[4];
    {
        const int colm = (col < 12) ? col : 0;
        #pragma unroll
        for (int r2 = 0; r2 < 4; ++r2) {
            int q = quad * 4 + r2; if (q > 11) q = 11;
            mrow[r2] = mask[q * 12 + colm];
        }
    }

    // -------- Softmax (rows over 16-lane quads) + write z (bf16) to zP --------
    f32x4 smats[4] = {sff, sfs, ssf, sss};
    #pragma unroll
    for (int mat = 0; mat < 4; ++mat) {
        float s[4], mx[4], p[4], sm[4];
        #pragma unroll
        for (int r2 = 0; r2 < 4; ++r2) {
            float v = smats[mat][r2] * 0.125f;          // scale BEFORE mask
            if (mrow[r2] != 0) v = -1e9f;               // reference NEG_INF
            if (col >= 12) v = -__builtin_inff();       // K-pad: true -inf -> z=0 exactly
            s[r2] = v; mx[r2] = v;
        }
        #pragma unroll
        for (int off = 1; off < 16; off <<= 1) {
            #pragma unroll
            for (int r2 = 0; r2 < 4; ++r2) mx[r2] = fmaxf(mx[r2], __shfl_xor(mx[r2], off));
        }
        #pragma unroll
        for (int r2 = 0; r2 < 4; ++r2) {
            p[r2] = exp2f((s[r2] - mx[r2]) * 1.4426950408889634f);
            sm[r2] = p[r2];
        }
        #pragma unroll
        for (int off = 1; off < 16; off <<= 1) {
            #pragma unroll
            for (int r2 = 0; r2 < 4; ++r2) sm[r2] += __shfl_xor(sm[r2], off);
        }
        #pragma unroll
        for (int r2 = 0; r2 < 4; ++r2) {
            float z = p[r2] / sm[r2];
            zp[mat * 512 + (quad * 4 + r2) * 32 + col] = f2bf(z);
        }
    }

    // -------- PV phase: A = z (from zP, A-layout), B = V^T (direct global) --------
    bf16x8 aP[4];
    #pragma unroll
    for (int mat = 0; mat < 4; ++mat)
        aP[mat] = *(const bf16x8*)(zp + mat * 512 + col * 32 + quad * 8);

    #pragma unroll
    for (int t = 0; t < 4; ++t) {   // N=64 -> 4 tiles of 16 d-columns
        bf16x8 vf, vs;
        #pragma unroll
        for (int j = 0; j < 8; ++j) {
            const int kt = quad * 8 + j;        // contraction index (time), pad >=12 with 0
            float a = 0.f, b = 0.f;
            if (kt < 12) {
                const long o = base + (long)kt * 64 + t * 16 + col;
                a = Vf[o]; b = Vs[o];
            }
            vf[j] = f2bf(a); vs[j] = f2bf(b);
        }
        f32x4 cff = __builtin_amdgcn_mfma_f32_16x16x32_bf16(aP[0], vf, zero4, 0, 0, 0);
        f32x4 cfs = __builtin_amdgcn_mfma_f32_16x16x32_bf16(aP[1], vf, zero4, 0, 0, 0);
        f32x4 csf = __builtin_amdgcn_mfma_f32_16x16x32_bf16(aP[2], vs, zero4, 0, 0, 0);
        f32x4 css = __builtin_amdgcn_mfma_f32_16x16x32_bf16(aP[3], vs, zero4, 0, 0, 0);
        #pragma unroll
        for (int r2 = 0; r2 < 4; ++r2) {
            const int q = quad * 4 + r2;
            if (q < 12) {
                const long o = base + (long)q * 64 + t * 16 + col;
                out[o]                  = cff[r2];
                out[o + MAT_STRIDE]     = cfs[r2];
                out[o + 2 * MAT_STRIDE] = csf[r2];
                out[o + 3 * MAT_STRIDE] = css[r2];
            }
        }
    }
}

extern "C" void kernel_launch(void* const* d_in, const int* in_sizes, int n_in,
                              void* d_out, int out_size, void* d_ws, size_t ws_size,
                              hipStream_t stream) {
    const float* Qf  = (const float*)d_in[0];
    const float* Kf  = (const float*)d_in[1];
    const float* Vf  = (const float*)d_in[2];
    const float* Qs  = (const float*)d_in[3];
    const float* Ks  = (const float*)d_in[4];
    const float* Vs  = (const float*)d_in[5];
    const float* Kj  = (const float*)d_in[6];
    const float* Vfp = (const float*)d_in[7];
    const int*   msk = (const int*)d_in[8];

    dim3 grid(NGROUPS / WAVES_PER_BLOCK);   // 39296 / 4 = 9824, exact
    dim3 block(256);
    tsdp_kernel<<<grid, block, 0, stream>>>(Qf, Kf, Vf, Qs, Ks, Vs, Kj, Vfp, msk,
                                            (float*)d_out);
}